// Round 20
// baseline (172.725 us; speedup 1.0000x reference)
//
#include <hip/hip_runtime.h>
#include <hip/hip_bf16.h>

// ---------------------------------------------------------------------------
// CrossFormerBlock on MI355X (gfx950)
// B=1 D=16 H=32 W=32 T=4 C=128, G=4, NH=8, HD=16, NW=256 windows, N=256 tok/win
// R20 (from R19 best=169.3us):
//  (1) DB=1 2-phase double-buffer extended to ALL GEMMs (validated on fc2 in
//      R19): next-tile gload issued before compute, one drain per tile.
//  (2) conv kept at R19 structure (stable ~39.5us floor after 6 attempts).
//  NOTE: border_zero CANNOT be folded into setup (y1p overlays q/k which qkv
//  writes after setup) — it stays a separate kernel after attn.
// ---------------------------------------------------------------------------

typedef __attribute__((ext_vector_type(8))) short  s16x8;
typedef __attribute__((ext_vector_type(4))) short  s16x4;
typedef __attribute__((ext_vector_type(4))) float  f32x4;
typedef __attribute__((ext_vector_type(8))) _Float16 f16x8;
typedef __attribute__((ext_vector_type(4))) _Float16 f16x4;

#define CC    128
#define NWIN  256
#define TOKS  65536
#define SCALE 0.25f
#define LNEPS 1e-5f
#define PD 18
#define PH 34
#define PW 34
#define PSITES (PD*PH*PW)                // 20808
#define PREP_BLOCKS 782
#define LN1_BLOCKS (TOKS/8)

__device__ __forceinline__ float b2f(short s) {
  union { unsigned u; float f; } c; c.u = ((unsigned)(unsigned short)s) << 16; return c.f;
}
__device__ __forceinline__ short f2b(float f) {
  __hip_bfloat16 h = __float2bfloat16(f);
  return *reinterpret_cast<short*>(&h);
}
__device__ __forceinline__ float fast_gelu(float x) {
  float u = 1.595769122f * x * fmaf(0.044715f, x*x, 1.0f);
  return x / (1.0f + __expf(-u));
}

__device__ __forceinline__ f32x4 mfma16x16x16_bf16(s16x4 a, s16x4 b, f32x4 c) {
#if __has_builtin(__builtin_amdgcn_mfma_f32_16x16x16_bf16)
  return __builtin_amdgcn_mfma_f32_16x16x16_bf16(a, b, c, 0, 0, 0);
#elif __has_builtin(__builtin_amdgcn_mfma_f32_16x16x16bf16_1k)
  return __builtin_amdgcn_mfma_f32_16x16x16bf16_1k(a, b, c, 0, 0, 0);
#else
  f32x4 d;
  asm("v_mfma_f32_16x16x16_bf16 %0, %1, %2, %3" : "=v"(d) : "v"(a), "v"(b), "v"(c));
  return d;
#endif
}

__device__ __forceinline__ void gload16(const short* g, short* l) {
  __builtin_amdgcn_global_load_lds(
      (const __attribute__((address_space(1))) void*)g,
      (__attribute__((address_space(3))) void*)l, 16, 0, 0);
}

// ---------------------------------------------------------------------------
// Kernel: SETUP = weight prep (blocks 0..781) + LN1+PE (blocks 782..)
// ---------------------------------------------------------------------------
__global__ __launch_bounds__(256) void setup_kernel(
    const float* __restrict__ qkv_w, const float* __restrict__ proj_w,
    const float* __restrict__ fc1_w, const float* __restrict__ fc2_w,
    const float* __restrict__ conv_w,
    __hip_bfloat16* wq, __hip_bfloat16* wp,
    __hip_bfloat16* w1, __hip_bfloat16* w2, float* cwT,
    const float* __restrict__ x, const float* __restrict__ g,
    const float* __restrict__ b, const float* __restrict__ pos,
    const float* __restrict__ te, __hip_bfloat16* __restrict__ hb) {
  if (blockIdx.x < PREP_BLOCKS) {
    int idx = blockIdx.x * 256 + threadIdx.x;
    if (idx < 49152) {
      wq[idx] = __float2bfloat16(qkv_w[idx]);
    } else if (idx < 65536) {
      wp[idx - 49152] = __float2bfloat16(proj_w[idx - 49152]);
    } else if (idx < 131072) {
      w1[idx - 65536] = __float2bfloat16(fc1_w[idx - 65536]);
    } else if (idx < 196608) {
      w2[idx - 131072] = __float2bfloat16(fc2_w[idx - 131072]);
    } else if (idx < 196608 + 27*128) {
      int j = idx - 196608;
      int tap = j >> 7, c = j & 127;
      cwT[tap*128 + c] = conv_w[c*27 + tap];
    }
    return;
  }
  const int tid = threadIdx.x;
  const int tk = (blockIdx.x - PREP_BLOCKS)*8 + (tid >> 5);
  const int c4 = (tid & 31) * 4;
  const int wid = tk >> 8, n = tk & 255;
  const int t = n >> 6, gd = (n >> 4) & 3, gh = (n >> 2) & 3, gw = n & 3;
  const int wd = wid >> 6, wh = (wid >> 3) & 7, ww = wid & 7;
  const int d = wd*4 + gd, h = wh*4 + gh, w = ww*4 + gw;
  const size_t xoff = ((size_t)((d*32 + h)*32 + w)*4 + t) * CC;
  f32x4 v = *(const f32x4*)&x[xoff + c4];
  float s  = (v.x + v.y) + (v.z + v.w);
  float sq = (v.x*v.x + v.y*v.y) + (v.z*v.z + v.w*v.w);
#pragma unroll
  for (int m = 1; m <= 16; m <<= 1) { s += __shfl_xor(s, m); sq += __shfl_xor(sq, m); }
  const float mean = s * (1.f/128.f);
  const float var  = sq * (1.f/128.f) - mean*mean;
  const float rstd = rsqrtf(var + LNEPS);
  const int pb = ((gd*4 + gh)*4 + gw) * CC, tb = t * CC;
  f32x4 gv = *(const f32x4*)&g[c4];
  f32x4 bv = *(const f32x4*)&b[c4];
  f32x4 pv = *(const f32x4*)&pos[pb + c4];
  f32x4 tv = *(const f32x4*)&te[tb + c4];
  s16x4 o;
  o[0] = f2b((v.x - mean)*rstd*gv.x + bv.x + pv.x + tv.x);
  o[1] = f2b((v.y - mean)*rstd*gv.y + bv.y + pv.y + tv.y);
  o[2] = f2b((v.z - mean)*rstd*gv.z + bv.z + pv.z + tv.z);
  o[3] = f2b((v.w - mean)*rstd*gv.w + bv.w + pv.w + tv.w);
  *(s16x4*)&((short*)hb)[(size_t)tk*CC + c4] = o;
}

// ---------------------------------------------------------------------------
// Kernel: zero only the BORDER sites of the padded y1 buffer.
// ---------------------------------------------------------------------------
__global__ __launch_bounds__(256) void border_zero_kernel(short* __restrict__ y1p) {
  int idx = blockIdx.x*256 + threadIdx.x;
  if (idx >= PSITES*64) return;
  int site = idx >> 6;
  int w = site % PW, hh = (site / PW) % PH, d = site / (PW*PH);
  if (d != 0 && d != PD-1 && hh != 0 && hh != PH-1 && w != 0 && w != PW-1) return;
  *(s16x8*)&y1p[(size_t)site*512 + (idx & 63)*8] = (s16x8)0;
}

// ---------------------------------------------------------------------------
// GEMM template: 128x128 tile, BK=64, 4 waves; 2-phase double-buffer for all.
// ---------------------------------------------------------------------------
template <int MODE, int KK>
__global__ __launch_bounds__(256) void gemm_kernel(
    const short* __restrict__ Ag, const short* __restrict__ Wg,
    const float* __restrict__ bias,
    void* __restrict__ out0, const _Float16* __restrict__ resid) {
  __shared__ __align__(16) short As[2][128*64];
  __shared__ __align__(16) short Bs[2][128*64];
  const int tid = threadIdx.x;
  const int m0 = blockIdx.x * 128;
  const int n0 = blockIdx.y * 128;
  const int lane = tid & 63, wv = tid >> 6;
  const int wr = wv >> 1, wc = wv & 1;
  const int fr = lane & 15, kg = lane >> 4;

  f32x4 acc[4][4];
#pragma unroll
  for (int i = 0; i < 4; ++i)
#pragma unroll
    for (int j = 0; j < 4; ++j) acc[i][j] = (f32x4)0.f;

  constexpr int NT = KK / 64;
#pragma unroll
  for (int i = 0; i < 4; ++i) {
    const int e = i*2048 + tid*8;
    const int row = e >> 6, col = e & 63;
    gload16(Ag + (size_t)(m0 + row)*KK + col, &As[0][i*2048 + wv*512]);
    gload16(Wg + (size_t)(n0 + row)*KK + col, &Bs[0][i*2048 + wv*512]);
  }
  __syncthreads();
#pragma unroll
  for (int t = 0; t < NT; ++t) {
    const int cur = t & 1;
    if (t + 1 < NT) {
      const int kc = (t + 1) * 64;
#pragma unroll
      for (int i = 0; i < 4; ++i) {
        const int e = i*2048 + tid*8;
        const int row = e >> 6, col = e & 63;
        gload16(Ag + (size_t)(m0 + row)*KK + kc + col, &As[cur^1][i*2048 + wv*512]);
        gload16(Wg + (size_t)(n0 + row)*KK + kc + col, &Bs[cur^1][i*2048 + wv*512]);
      }
    }
#pragma unroll
    for (int ks = 0; ks < 2; ++ks) {
      s16x8 a[4], b[4];
#pragma unroll
      for (int i = 0; i < 4; ++i)
        a[i] = *(const s16x8*)&As[cur][(wr*64 + i*16 + fr)*64 + ks*32 + kg*8];
#pragma unroll
      for (int j = 0; j < 4; ++j)
        b[j] = *(const s16x8*)&Bs[cur][(wc*64 + j*16 + fr)*64 + ks*32 + kg*8];
#pragma unroll
      for (int i = 0; i < 4; ++i)
#pragma unroll
        for (int j = 0; j < 4; ++j)
          acc[i][j] = __builtin_amdgcn_mfma_f32_16x16x32_bf16(b[j], a[i], acc[i][j], 0, 0, 0);
    }
    __syncthreads();
  }

  const int nbb = n0 + wc*64 + kg*4;
  f32x4 bj4[4];
#pragma unroll
  for (int j = 0; j < 4; ++j) bj4[j] = *(const f32x4*)&bias[nbb + j*16];

#pragma unroll
  for (int i = 0; i < 4; ++i) {
    const int m = m0 + wr*64 + i*16 + fr;
    if constexpr (MODE == 0) {
      short* qs = (short*)out0;
      const int sec = n0 >> 7;
      const float scl = (sec == 0) ? SCALE : 1.0f;
      const int wid = m >> 8, ntok = m & 255;
      const int rowbase = sec*8388608 + (wid*8)*4096 + ntok*16 + (nbb & 15);
#pragma unroll
      for (int j = 0; j < 4; ++j) {
        const int head = ((nbb + j*16) >> 4) & 7;
        f32x4 v = acc[i][j];
        s16x4 o;
        o[0] = f2b(fmaf(v[0], scl, bj4[j].x*scl));
        o[1] = f2b(fmaf(v[1], scl, bj4[j].y*scl));
        o[2] = f2b(fmaf(v[2], scl, bj4[j].z*scl));
        o[3] = f2b(fmaf(v[3], scl, bj4[j].w*scl));
        *(s16x4*)&qs[rowbase + head*4096] = o;
      }
    } else if constexpr (MODE == 1) {
      short* y1o = (short*)out0;
      const int wid = m >> 8, ntok = m & 255;
      const int t = ntok >> 6, gd = (ntok >> 4) & 3, gh = (ntok >> 2) & 3, gw = ntok & 3;
      const int wd = wid >> 6, wh = (wid >> 3) & 7, ww = wid & 7;
      const int sr = (((wd*4 + gd + 1)*PH + wh*4 + gh + 1)*PW + ww*4 + gw + 1)*4 + t;
      const int base = sr*CC + nbb;
#pragma unroll
      for (int j = 0; j < 4; ++j) {
        f32x4 v = acc[i][j];
        s16x4 o;
        o[0] = f2b(v[0] + bj4[j].x); o[1] = f2b(v[1] + bj4[j].y);
        o[2] = f2b(v[2] + bj4[j].z); o[3] = f2b(v[3] + bj4[j].w);
        *(s16x4*)&y1o[base + j*16] = o;
      }
    } else if constexpr (MODE == 2) {
      short* gp = (short*)out0;
      const int base = m*512 + nbb;
#pragma unroll
      for (int j = 0; j < 4; ++j) {
        f32x4 v = acc[i][j];
        s16x4 o;
        o[0] = f2b(fast_gelu(v[0] + bj4[j].x)); o[1] = f2b(fast_gelu(v[1] + bj4[j].y));
        o[2] = f2b(fast_gelu(v[2] + bj4[j].z)); o[3] = f2b(fast_gelu(v[3] + bj4[j].w));
        *(s16x4*)&gp[base + j*16] = o;
      }
    } else {
      float* outp = (float*)out0;
      const int base = m*CC + nbb;
#pragma unroll
      for (int j = 0; j < 4; ++j) {
        f32x4 v = acc[i][j];
        f16x4 rz = *(const f16x4*)&resid[base + j*16];
        f32x4 o;
        o.x = v[0] + bj4[j].x + (float)rz[0]; o.y = v[1] + bj4[j].y + (float)rz[1];
        o.z = v[2] + bj4[j].z + (float)rz[2]; o.w = v[3] + bj4[j].w + (float)rz[3];
        *(f32x4*)&outp[base + j*16] = o;
      }
    }
  }
}

// ---------------------------------------------------------------------------
// Kernel: MFMA window attention (unchanged from R2).
// ---------------------------------------------------------------------------
#define KPAD 20
#define VPAD 264
__global__ __launch_bounds__(256) void attn_mfma_kernel(
    const __hip_bfloat16* __restrict__ qb, const __hip_bfloat16* __restrict__ kb,
    const __hip_bfloat16* __restrict__ vb, __hip_bfloat16* __restrict__ ob) {
  __shared__ __align__(16) short kL[256*KPAD];
  __shared__ __align__(16) short vT[16*VPAD];
  const int bh = blockIdx.x;
  const int wid = bh >> 3, head = bh & 7;
  const int tid = threadIdx.x;
  const short* kg = (const short*)kb + (size_t)bh*4096;
  const short* vg = (const short*)vb + (size_t)bh*4096;
  const short* qg = (const short*)qb + (size_t)bh*4096;
  {
    s16x8 a0 = *(const s16x8*)&kg[tid*16];
    s16x8 a1 = *(const s16x8*)&kg[tid*16 + 8];
    *(s16x8*)&kL[tid*KPAD]     = a0;
    *(s16x8*)&kL[tid*KPAD + 8] = a1;
    s16x8 b0 = *(const s16x8*)&vg[tid*16];
    s16x8 b1 = *(const s16x8*)&vg[tid*16 + 8];
#pragma unroll
    for (int d = 0; d < 8; ++d) {
      vT[d*VPAD + tid]     = b0[d];
      vT[(d+8)*VPAD + tid] = b1[d];
    }
  }
  __syncthreads();
  const int wv = tid >> 6, lane = tid & 63;
  const int fr = lane & 15, hi = lane >> 4;
  s16x4 kfrag[16], vfrag[16];
#pragma unroll
  for (int t = 0; t < 16; ++t) {
    kfrag[t] = *(const s16x4*)&kL[(t*16 + fr)*KPAD + hi*4];
    vfrag[t] = *(const s16x4*)&vT[fr*VPAD + t*16 + hi*4];
  }
  short* obs = (short*)ob;
  for (int qt = 0; qt < 4; ++qt) {
    const int q0 = wv*64 + qt*16;
    s16x4 qfrag = *(const s16x4*)&qg[(q0 + fr)*16 + hi*4];
    f32x4 st[16];
#pragma unroll
    for (int kt = 0; kt < 16; ++kt)
      st[kt] = mfma16x16x16_bf16(kfrag[kt], qfrag, (f32x4)0.f);
    float den = 0.f;
    f32x4 oacc = (f32x4)0.f;
#pragma unroll
    for (int kt = 0; kt < 16; ++kt) {
      float e0 = __expf(st[kt][0]), e1 = __expf(st[kt][1]);
      float e2 = __expf(st[kt][2]), e3 = __expf(st[kt][3]);
      den += (e0 + e1) + (e2 + e3);
      s16x4 pa;
      pa[0] = f2b(e0); pa[1] = f2b(e1); pa[2] = f2b(e2); pa[3] = f2b(e3);
      oacc = mfma16x16x16_bf16(vfrag[kt], pa, oacc);
    }
    den += __shfl_xor(den, 16);
    den += __shfl_xor(den, 32);
    float inv = 1.f / den;
    s16x4 ov;
    ov[0] = f2b(oacc[0]*inv); ov[1] = f2b(oacc[1]*inv);
    ov[2] = f2b(oacc[2]*inv); ov[3] = f2b(oacc[3]*inv);
    *(s16x4*)&obs[((size_t)wid*256 + q0 + fr)*CC + head*16 + hi*4] = ov;
  }
}

// ---------------------------------------------------------------------------
// Kernel: FUSED conv3x3x3 + exln + norm2 (R19 2-t-chain structure).
// ---------------------------------------------------------------------------
__global__ __launch_bounds__(256) void conv_ln_kernel(
    const __hip_bfloat16* __restrict__ y1p, const float* __restrict__ wT,
    const float* __restrict__ cb,
    const float* __restrict__ exg, const float* __restrict__ exb,
    const float* __restrict__ n2g, const float* __restrict__ n2b,
    _Float16* __restrict__ yb, __hip_bfloat16* __restrict__ h2) {
  const int tid = threadIdx.x;
  const int sp = blockIdx.x*8 + (tid >> 5);
  const int tp = (tid >> 4) & 1;
  const int cbase = (tid & 15) * 8;
  const int w = sp & 31, h = (sp >> 5) & 31, d = sp >> 10;
  const int psite = ((d+1)*PH + (h+1))*PW + (w+1);
  const short* base = (const short*)y1p + (size_t)psite*512 + tp*2*CC + cbase;

  float acc[2][8];
  {
    f32x4 cb0 = *(const f32x4*)&cb[cbase];
    f32x4 cb1 = *(const f32x4*)&cb[cbase + 4];
#pragma unroll
    for (int t = 0; t < 2; ++t) {
      acc[t][0]=cb0.x; acc[t][1]=cb0.y; acc[t][2]=cb0.z; acc[t][3]=cb0.w;
      acc[t][4]=cb1.x; acc[t][5]=cb1.y; acc[t][6]=cb1.z; acc[t][7]=cb1.w;
    }
  }

#pragma unroll
  for (int dd = -1; dd <= 1; ++dd)
#pragma unroll
    for (int dh = -1; dh <= 1; ++dh)
#pragma unroll
      for (int dw = -1; dw <= 1; ++dw) {
        const int tap = ((dd+1)*3 + (dh+1))*3 + (dw+1);
        const int toff = ((dd*PH + dh)*PW + dw)*512;
        f32x4 w0 = *(const f32x4*)&wT[tap*CC + cbase];
        f32x4 w1 = *(const f32x4*)&wT[tap*CC + cbase + 4];
#pragma unroll
        for (int t = 0; t < 2; ++t) {
          s16x8 v = *(const s16x8*)(base + toff + t*CC);
          acc[t][0] = fmaf(b2f(v[0]), w0.x, acc[t][0]);
          acc[t][1] = fmaf(b2f(v[1]), w0.y, acc[t][1]);
          acc[t][2] = fmaf(b2f(v[2]), w0.z, acc[t][2]);
          acc[t][3] = fmaf(b2f(v[3]), w0.w, acc[t][3]);
          acc[t][4] = fmaf(b2f(v[4]), w1.x, acc[t][4]);
          acc[t][5] = fmaf(b2f(v[5]), w1.y, acc[t][5]);
          acc[t][6] = fmaf(b2f(v[6]), w1.z, acc[t][6]);
          acc[t][7] = fmaf(b2f(v[7]), w1.w, acc[t][7]);
        }
      }

  f32x4 eg0 = *(const f32x4*)&exg[cbase], eg1 = *(const f32x4*)&exg[cbase+4];
  f32x4 eb0 = *(const f32x4*)&exb[cbase], eb1 = *(const f32x4*)&exb[cbase+4];
  f32x4 ng0 = *(const f32x4*)&n2g[cbase], ng1 = *(const f32x4*)&n2g[cbase+4];
  f32x4 nb0 = *(const f32x4*)&n2b[cbase], nb1 = *(const f32x4*)&n2b[cbase+4];
  float eg[8] = {eg0.x,eg0.y,eg0.z,eg0.w,eg1.x,eg1.y,eg1.z,eg1.w};
  float eb[8] = {eb0.x,eb0.y,eb0.z,eb0.w,eb1.x,eb1.y,eb1.z,eb1.w};
  float ng[8] = {ng0.x,ng0.y,ng0.z,ng0.w,ng1.x,ng1.y,ng1.z,ng1.w};
  float nb[8] = {nb0.x,nb0.y,nb0.z,nb0.w,nb1.x,nb1.y,nb1.z,nb1.w};

#pragma unroll
  for (int t = 0; t < 2; ++t) {
    float s = 0.f, sq = 0.f;
#pragma unroll
    for (int c = 0; c < 8; ++c) { s += acc[t][c]; sq = fmaf(acc[t][c], acc[t][c], sq); }
#pragma unroll
    for (int m = 1; m <= 8; m <<= 1) { s += __shfl_xor(s, m); sq += __shfl_xor(sq, m); }
    float mean = s * (1.f/128.f);
    float var  = sq * (1.f/128.f) - mean*mean;
    float rstd = rsqrtf(var + LNEPS);
    float y[8];
    f16x8 yo;
#pragma unroll
    for (int c = 0; c < 8; ++c) {
      y[c] = (acc[t][c] - mean)*rstd*eg[c] + eb[c];
      yo[c] = (_Float16)y[c];
    }
    const int tok = sp*4 + tp*2 + t;
    *(f16x8*)&yb[(size_t)tok*CC + cbase] = yo;
    float s2 = 0.f, sq2 = 0.f;
#pragma unroll
    for (int c = 0; c < 8; ++c) { s2 += y[c]; sq2 = fmaf(y[c], y[c], sq2); }
#pragma unroll
    for (int m = 1; m <= 8; m <<= 1) { s2 += __shfl_xor(s2, m); sq2 += __shfl_xor(sq2, m); }
    float mean2 = s2 * (1.f/128.f);
    float var2  = sq2 * (1.f/128.f) - mean2*mean2;
    float rstd2 = rsqrtf(var2 + LNEPS);
    s16x8 ho;
#pragma unroll
    for (int c = 0; c < 8; ++c)
      ho[c] = f2b((y[c] - mean2)*rstd2*ng[c] + nb[c]);
    *(s16x8*)&((short*)h2)[(size_t)tok*CC + cbase] = ho;
  }
}

// ---------------------------------------------------------------------------
// Launch
// ---------------------------------------------------------------------------
extern "C" void kernel_launch(void* const* d_in, const int* in_sizes, int n_in,
                              void* d_out, int out_size, void* d_ws, size_t ws_size,
                              hipStream_t stream) {
  const float* x      = (const float*)d_in[0];
  const float* n1g    = (const float*)d_in[1];
  const float* n1b    = (const float*)d_in[2];
  const float* pos    = (const float*)d_in[3];
  const float* te     = (const float*)d_in[4];
  const float* qkv_w  = (const float*)d_in[5];
  const float* qkv_b  = (const float*)d_in[6];
  const float* proj_w = (const float*)d_in[7];
  const float* proj_b = (const float*)d_in[8];
  const float* conv_w = (const float*)d_in[9];
  const float* conv_b = (const float*)d_in[10];
  const float* exg    = (const float*)d_in[11];
  const float* exb    = (const float*)d_in[12];
  const float* n2g    = (const float*)d_in[13];
  const float* n2b    = (const float*)d_in[14];
  const float* fc1_w  = (const float*)d_in[15];
  const float* fc1_b  = (const float*)d_in[16];
  const float* fc2_w  = (const float*)d_in[17];
  const float* fc2_b  = (const float*)d_in[18];

  char* wsb = (char*)d_ws;
  __hip_bfloat16* wq  = (__hip_bfloat16*)(wsb);
  __hip_bfloat16* wp  = (__hip_bfloat16*)(wsb + 98304);
  __hip_bfloat16* w1  = (__hip_bfloat16*)(wsb + 131072);
  __hip_bfloat16* w2  = (__hip_bfloat16*)(wsb + 262144);
  float*          cwT = (float*)(wsb + 393216);

  const size_t A_OFF = (size_t)1 << 20;
  const size_t B_OFF = A_OFF + ((size_t)16 << 20);
  const size_t C_OFF = B_OFF + ((size_t)48 << 20);

  __hip_bfloat16* hbuf = (__hip_bfloat16*)(wsb + A_OFF);
  __hip_bfloat16* obuf = (__hip_bfloat16*)(wsb + A_OFF);
  __hip_bfloat16* h2in = (__hip_bfloat16*)(wsb + A_OFF);
  __hip_bfloat16* qkvb = (__hip_bfloat16*)(wsb + B_OFF);
  __hip_bfloat16* qb   = qkvb;
  __hip_bfloat16* kb   = qkvb + 8388608;
  __hip_bfloat16* vb   = qkvb + 16777216;
  __hip_bfloat16* y1p  = (__hip_bfloat16*)(wsb + B_OFF);
  _Float16* yb = (_Float16*)(wsb + B_OFF + ((size_t)24 << 20));
  __hip_bfloat16* gbuf = (__hip_bfloat16*)(wsb + C_OFF);

  setup_kernel<<<PREP_BLOCKS + LN1_BLOCKS, 256, 0, stream>>>(
      qkv_w, proj_w, fc1_w, fc2_w, conv_w, wq, wp, w1, w2, cwT,
      x, n1g, n1b, pos, te, hbuf);
  gemm_kernel<0, 128><<<dim3(TOKS/128, 3), 256, 0, stream>>>(
      (const short*)hbuf, (const short*)wq, qkv_b, (void*)qkvb, nullptr);
  attn_mfma_kernel<<<NWIN*8, 256, 0, stream>>>(qb, kb, vb, obuf);
  border_zero_kernel<<<(PSITES*64 + 255)/256, 256, 0, stream>>>((short*)y1p);
  gemm_kernel<1, 128><<<dim3(TOKS/128, 1), 256, 0, stream>>>(
      (const short*)obuf, (const short*)wp, proj_b, (void*)y1p, nullptr);
  conv_ln_kernel<<<16384/8, 256, 0, stream>>>(y1p, cwT, conv_b,
      exg, exb, n2g, n2b, yb, h2in);
  gemm_kernel<2, 128><<<dim3(TOKS/128, 4), 256, 0, stream>>>(
      (const short*)h2in, (const short*)w1, fc1_b, (void*)gbuf, nullptr);
  gemm_kernel<3, 512><<<dim3(TOKS/128, 1), 256, 0, stream>>>(
      (const short*)gbuf, (const short*)w2, fc2_b, (void*)d_out, yb);
}

// Round 21
// 168.933 us; speedup vs baseline: 1.0225x; 1.0225x over previous
//
#include <hip/hip_runtime.h>
#include <hip/hip_bf16.h>

// ---------------------------------------------------------------------------
// CrossFormerBlock on MI355X (gfx950)
// B=1 D=16 H=32 W=32 T=4 C=128, G=4, NH=8, HD=16, NW=256 windows, N=256 tok/win
// R21: exact restore of R19 (best measured 169.35us). R20 proved DB=1 on the
// K=128 GEMMs trades 3->2 blocks/CU for one prefetch and loses ~3us; DB=1
// stays only on fc2 (K=512, NT=8). Conv at its 6-attempt structural floor.
// ---------------------------------------------------------------------------

typedef __attribute__((ext_vector_type(8))) short  s16x8;
typedef __attribute__((ext_vector_type(4))) short  s16x4;
typedef __attribute__((ext_vector_type(4))) float  f32x4;
typedef __attribute__((ext_vector_type(8))) _Float16 f16x8;
typedef __attribute__((ext_vector_type(4))) _Float16 f16x4;

#define CC    128
#define NWIN  256
#define TOKS  65536
#define SCALE 0.25f
#define LNEPS 1e-5f
#define PD 18
#define PH 34
#define PW 34
#define PSITES (PD*PH*PW)                // 20808
#define PREP_BLOCKS 782
#define LN1_BLOCKS (TOKS/8)

__device__ __forceinline__ float b2f(short s) {
  union { unsigned u; float f; } c; c.u = ((unsigned)(unsigned short)s) << 16; return c.f;
}
__device__ __forceinline__ short f2b(float f) {
  __hip_bfloat16 h = __float2bfloat16(f);
  return *reinterpret_cast<short*>(&h);
}
__device__ __forceinline__ float fast_gelu(float x) {
  float u = 1.595769122f * x * fmaf(0.044715f, x*x, 1.0f);
  return x / (1.0f + __expf(-u));
}

__device__ __forceinline__ f32x4 mfma16x16x16_bf16(s16x4 a, s16x4 b, f32x4 c) {
#if __has_builtin(__builtin_amdgcn_mfma_f32_16x16x16_bf16)
  return __builtin_amdgcn_mfma_f32_16x16x16_bf16(a, b, c, 0, 0, 0);
#elif __has_builtin(__builtin_amdgcn_mfma_f32_16x16x16bf16_1k)
  return __builtin_amdgcn_mfma_f32_16x16x16bf16_1k(a, b, c, 0, 0, 0);
#else
  f32x4 d;
  asm("v_mfma_f32_16x16x16_bf16 %0, %1, %2, %3" : "=v"(d) : "v"(a), "v"(b), "v"(c));
  return d;
#endif
}

// async global->LDS, 16B per lane; lds base wave-uniform (HW appends lane*16).
__device__ __forceinline__ void gload16(const short* g, short* l) {
  __builtin_amdgcn_global_load_lds(
      (const __attribute__((address_space(1))) void*)g,
      (__attribute__((address_space(3))) void*)l, 16, 0, 0);
}

// ---------------------------------------------------------------------------
// Kernel: SETUP = weight prep (blocks 0..781) + LN1+PE (blocks 782..)
// ---------------------------------------------------------------------------
__global__ __launch_bounds__(256) void setup_kernel(
    const float* __restrict__ qkv_w, const float* __restrict__ proj_w,
    const float* __restrict__ fc1_w, const float* __restrict__ fc2_w,
    const float* __restrict__ conv_w,
    __hip_bfloat16* wq, __hip_bfloat16* wp,
    __hip_bfloat16* w1, __hip_bfloat16* w2, float* cwT,
    const float* __restrict__ x, const float* __restrict__ g,
    const float* __restrict__ b, const float* __restrict__ pos,
    const float* __restrict__ te, __hip_bfloat16* __restrict__ hb) {
  if (blockIdx.x < PREP_BLOCKS) {
    int idx = blockIdx.x * 256 + threadIdx.x;
    if (idx < 49152) {
      wq[idx] = __float2bfloat16(qkv_w[idx]);
    } else if (idx < 65536) {
      wp[idx - 49152] = __float2bfloat16(proj_w[idx - 49152]);
    } else if (idx < 131072) {
      w1[idx - 65536] = __float2bfloat16(fc1_w[idx - 65536]);
    } else if (idx < 196608) {
      w2[idx - 131072] = __float2bfloat16(fc2_w[idx - 131072]);
    } else if (idx < 196608 + 27*128) {
      int j = idx - 196608;
      int tap = j >> 7, c = j & 127;
      cwT[tap*128 + c] = conv_w[c*27 + tap];   // (C,1,3,3,3) -> (27,C)
    }
    return;
  }
  // ---- LN1 + PE: 32 lanes/token, f32x4 loads ----
  const int tid = threadIdx.x;
  const int tk = (blockIdx.x - PREP_BLOCKS)*8 + (tid >> 5);
  const int c4 = (tid & 31) * 4;
  const int wid = tk >> 8, n = tk & 255;
  const int t = n >> 6, gd = (n >> 4) & 3, gh = (n >> 2) & 3, gw = n & 3;
  const int wd = wid >> 6, wh = (wid >> 3) & 7, ww = wid & 7;
  const int d = wd*4 + gd, h = wh*4 + gh, w = ww*4 + gw;
  const size_t xoff = ((size_t)((d*32 + h)*32 + w)*4 + t) * CC;
  f32x4 v = *(const f32x4*)&x[xoff + c4];
  float s  = (v.x + v.y) + (v.z + v.w);
  float sq = (v.x*v.x + v.y*v.y) + (v.z*v.z + v.w*v.w);
#pragma unroll
  for (int m = 1; m <= 16; m <<= 1) { s += __shfl_xor(s, m); sq += __shfl_xor(sq, m); }
  const float mean = s * (1.f/128.f);
  const float var  = sq * (1.f/128.f) - mean*mean;
  const float rstd = rsqrtf(var + LNEPS);
  const int pb = ((gd*4 + gh)*4 + gw) * CC, tb = t * CC;
  f32x4 gv = *(const f32x4*)&g[c4];
  f32x4 bv = *(const f32x4*)&b[c4];
  f32x4 pv = *(const f32x4*)&pos[pb + c4];
  f32x4 tv = *(const f32x4*)&te[tb + c4];
  s16x4 o;
  o[0] = f2b((v.x - mean)*rstd*gv.x + bv.x + pv.x + tv.x);
  o[1] = f2b((v.y - mean)*rstd*gv.y + bv.y + pv.y + tv.y);
  o[2] = f2b((v.z - mean)*rstd*gv.z + bv.z + pv.z + tv.z);
  o[3] = f2b((v.w - mean)*rstd*gv.w + bv.w + pv.w + tv.w);
  *(s16x4*)&((short*)hb)[(size_t)tk*CC + c4] = o;
}

// ---------------------------------------------------------------------------
// Kernel: zero only the BORDER sites of the padded y1 buffer (4424 sites).
// ---------------------------------------------------------------------------
__global__ __launch_bounds__(256) void border_zero_kernel(short* __restrict__ y1p) {
  int idx = blockIdx.x*256 + threadIdx.x;
  if (idx >= PSITES*64) return;
  int site = idx >> 6;
  int w = site % PW, hh = (site / PW) % PH, d = site / (PW*PH);
  if (d != 0 && d != PD-1 && hh != 0 && hh != PH-1 && w != 0 && w != PW-1) return;
  *(s16x8*)&y1p[(size_t)site*512 + (idx & 63)*8] = (s16x8)0;
}

// ---------------------------------------------------------------------------
// GEMM template: 128x128 tile, BK=64, 4 waves, compile-time K (KK).
// Staging: global_load_lds width=16, LINEAR LDS [128][64].
// DB=0: single-buffer 2-barrier loop (32KB LDS -> 3 blocks/CU).
// DB=1 (fc2 only, K=512): 2-phase double-buffer, one drain per tile.
// MODE 0: qkv split; MODE 1: proj -> PADDED spatial scatter bf16;
// MODE 2: fc1 + fast GELU; MODE 3: fc2 + bias + fp16 residual -> fp32 d_out
// ---------------------------------------------------------------------------
template <int MODE, int KK, int DB>
__global__ __launch_bounds__(256) void gemm_kernel(
    const short* __restrict__ Ag, const short* __restrict__ Wg,
    const float* __restrict__ bias,
    void* __restrict__ out0, const _Float16* __restrict__ resid) {
  __shared__ __align__(16) short As[DB + 1][128*64];
  __shared__ __align__(16) short Bs[DB + 1][128*64];
  const int tid = threadIdx.x;
  const int m0 = blockIdx.x * 128;
  const int n0 = blockIdx.y * 128;
  const int lane = tid & 63, wv = tid >> 6;
  const int wr = wv >> 1, wc = wv & 1;
  const int fr = lane & 15, kg = lane >> 4;

  f32x4 acc[4][4];
#pragma unroll
  for (int i = 0; i < 4; ++i)
#pragma unroll
    for (int j = 0; j < 4; ++j) acc[i][j] = (f32x4)0.f;

  if constexpr (DB == 0) {
#pragma unroll
    for (int kc = 0; kc < KK; kc += 64) {
      __syncthreads();
#pragma unroll
      for (int i = 0; i < 4; ++i) {
        const int e = i*2048 + tid*8;
        const int row = e >> 6, col = e & 63;
        gload16(Ag + (size_t)(m0 + row)*KK + kc + col, &As[0][i*2048 + wv*512]);
        gload16(Wg + (size_t)(n0 + row)*KK + kc + col, &Bs[0][i*2048 + wv*512]);
      }
      __syncthreads();
#pragma unroll
      for (int ks = 0; ks < 2; ++ks) {
        s16x8 a[4], b[4];
#pragma unroll
        for (int i = 0; i < 4; ++i)
          a[i] = *(const s16x8*)&As[0][(wr*64 + i*16 + fr)*64 + ks*32 + kg*8];
#pragma unroll
        for (int j = 0; j < 4; ++j)
          b[j] = *(const s16x8*)&Bs[0][(wc*64 + j*16 + fr)*64 + ks*32 + kg*8];
#pragma unroll
        for (int i = 0; i < 4; ++i)
#pragma unroll
          for (int j = 0; j < 4; ++j)
            acc[i][j] = __builtin_amdgcn_mfma_f32_16x16x32_bf16(b[j], a[i], acc[i][j], 0, 0, 0);
      }
    }
  } else {
    constexpr int NT = KK / 64;
#pragma unroll
    for (int i = 0; i < 4; ++i) {
      const int e = i*2048 + tid*8;
      const int row = e >> 6, col = e & 63;
      gload16(Ag + (size_t)(m0 + row)*KK + col, &As[0][i*2048 + wv*512]);
      gload16(Wg + (size_t)(n0 + row)*KK + col, &Bs[0][i*2048 + wv*512]);
    }
    __syncthreads();
#pragma unroll
    for (int t = 0; t < NT; ++t) {
      const int cur = t & 1;
      if (t + 1 < NT) {
        const int kc = (t + 1) * 64;
#pragma unroll
        for (int i = 0; i < 4; ++i) {
          const int e = i*2048 + tid*8;
          const int row = e >> 6, col = e & 63;
          gload16(Ag + (size_t)(m0 + row)*KK + kc + col, &As[cur^1][i*2048 + wv*512]);
          gload16(Wg + (size_t)(n0 + row)*KK + kc + col, &Bs[cur^1][i*2048 + wv*512]);
        }
      }
#pragma unroll
      for (int ks = 0; ks < 2; ++ks) {
        s16x8 a[4], b[4];
#pragma unroll
        for (int i = 0; i < 4; ++i)
          a[i] = *(const s16x8*)&As[cur][(wr*64 + i*16 + fr)*64 + ks*32 + kg*8];
#pragma unroll
        for (int j = 0; j < 4; ++j)
          b[j] = *(const s16x8*)&Bs[cur][(wc*64 + j*16 + fr)*64 + ks*32 + kg*8];
#pragma unroll
        for (int i = 0; i < 4; ++i)
#pragma unroll
          for (int j = 0; j < 4; ++j)
            acc[i][j] = __builtin_amdgcn_mfma_f32_16x16x32_bf16(b[j], a[i], acc[i][j], 0, 0, 0);
      }
      __syncthreads();
    }
  }

  const int nbb = n0 + wc*64 + kg*4;
  f32x4 bj4[4];
#pragma unroll
  for (int j = 0; j < 4; ++j) bj4[j] = *(const f32x4*)&bias[nbb + j*16];

#pragma unroll
  for (int i = 0; i < 4; ++i) {
    const int m = m0 + wr*64 + i*16 + fr;
    if constexpr (MODE == 0) {
      short* qs = (short*)out0;
      const int sec = n0 >> 7;
      const float scl = (sec == 0) ? SCALE : 1.0f;
      const int wid = m >> 8, ntok = m & 255;
      const int rowbase = sec*8388608 + (wid*8)*4096 + ntok*16 + (nbb & 15);
#pragma unroll
      for (int j = 0; j < 4; ++j) {
        const int head = ((nbb + j*16) >> 4) & 7;
        f32x4 v = acc[i][j];
        s16x4 o;
        o[0] = f2b(fmaf(v[0], scl, bj4[j].x*scl));
        o[1] = f2b(fmaf(v[1], scl, bj4[j].y*scl));
        o[2] = f2b(fmaf(v[2], scl, bj4[j].z*scl));
        o[3] = f2b(fmaf(v[3], scl, bj4[j].w*scl));
        *(s16x4*)&qs[rowbase + head*4096] = o;
      }
    } else if constexpr (MODE == 1) {
      short* y1o = (short*)out0;       // PADDED [18][34][34][4][128]
      const int wid = m >> 8, ntok = m & 255;
      const int t = ntok >> 6, gd = (ntok >> 4) & 3, gh = (ntok >> 2) & 3, gw = ntok & 3;
      const int wd = wid >> 6, wh = (wid >> 3) & 7, ww = wid & 7;
      const int sr = (((wd*4 + gd + 1)*PH + wh*4 + gh + 1)*PW + ww*4 + gw + 1)*4 + t;
      const int base = sr*CC + nbb;
#pragma unroll
      for (int j = 0; j < 4; ++j) {
        f32x4 v = acc[i][j];
        s16x4 o;
        o[0] = f2b(v[0] + bj4[j].x); o[1] = f2b(v[1] + bj4[j].y);
        o[2] = f2b(v[2] + bj4[j].z); o[3] = f2b(v[3] + bj4[j].w);
        *(s16x4*)&y1o[base + j*16] = o;
      }
    } else if constexpr (MODE == 2) {
      short* gp = (short*)out0;
      const int base = m*512 + nbb;
#pragma unroll
      for (int j = 0; j < 4; ++j) {
        f32x4 v = acc[i][j];
        s16x4 o;
        o[0] = f2b(fast_gelu(v[0] + bj4[j].x)); o[1] = f2b(fast_gelu(v[1] + bj4[j].y));
        o[2] = f2b(fast_gelu(v[2] + bj4[j].z)); o[3] = f2b(fast_gelu(v[3] + bj4[j].w));
        *(s16x4*)&gp[base + j*16] = o;
      }
    } else {
      float* outp = (float*)out0;
      const int base = m*CC + nbb;
#pragma unroll
      for (int j = 0; j < 4; ++j) {
        f32x4 v = acc[i][j];
        f16x4 rz = *(const f16x4*)&resid[base + j*16];
        f32x4 o;
        o.x = v[0] + bj4[j].x + (float)rz[0]; o.y = v[1] + bj4[j].y + (float)rz[1];
        o.z = v[2] + bj4[j].z + (float)rz[2]; o.w = v[3] + bj4[j].w + (float)rz[3];
        *(f32x4*)&outp[base + j*16] = o;
      }
    }
  }
}

// ---------------------------------------------------------------------------
// Kernel: MFMA window attention (unchanged from R2).
// ---------------------------------------------------------------------------
#define KPAD 20
#define VPAD 264
__global__ __launch_bounds__(256) void attn_mfma_kernel(
    const __hip_bfloat16* __restrict__ qb, const __hip_bfloat16* __restrict__ kb,
    const __hip_bfloat16* __restrict__ vb, __hip_bfloat16* __restrict__ ob) {
  __shared__ __align__(16) short kL[256*KPAD];
  __shared__ __align__(16) short vT[16*VPAD];
  const int bh = blockIdx.x;                // win*8 + head
  const int wid = bh >> 3, head = bh & 7;
  const int tid = threadIdx.x;
  const short* kg = (const short*)kb + (size_t)bh*4096;
  const short* vg = (const short*)vb + (size_t)bh*4096;
  const short* qg = (const short*)qb + (size_t)bh*4096;
  {
    s16x8 a0 = *(const s16x8*)&kg[tid*16];
    s16x8 a1 = *(const s16x8*)&kg[tid*16 + 8];
    *(s16x8*)&kL[tid*KPAD]     = a0;
    *(s16x8*)&kL[tid*KPAD + 8] = a1;
    s16x8 b0 = *(const s16x8*)&vg[tid*16];
    s16x8 b1 = *(const s16x8*)&vg[tid*16 + 8];
#pragma unroll
    for (int d = 0; d < 8; ++d) {
      vT[d*VPAD + tid]     = b0[d];
      vT[(d+8)*VPAD + tid] = b1[d];
    }
  }
  __syncthreads();
  const int wv = tid >> 6, lane = tid & 63;
  const int fr = lane & 15, hi = lane >> 4;
  s16x4 kfrag[16], vfrag[16];
#pragma unroll
  for (int t = 0; t < 16; ++t) {
    kfrag[t] = *(const s16x4*)&kL[(t*16 + fr)*KPAD + hi*4];
    vfrag[t] = *(const s16x4*)&vT[fr*VPAD + t*16 + hi*4];
  }
  short* obs = (short*)ob;
  for (int qt = 0; qt < 4; ++qt) {
    const int q0 = wv*64 + qt*16;
    s16x4 qfrag = *(const s16x4*)&qg[(q0 + fr)*16 + hi*4];
    f32x4 st[16];
#pragma unroll
    for (int kt = 0; kt < 16; ++kt)
      st[kt] = mfma16x16x16_bf16(kfrag[kt], qfrag, (f32x4)0.f);
    float den = 0.f;
    f32x4 oacc = (f32x4)0.f;
#pragma unroll
    for (int kt = 0; kt < 16; ++kt) {
      float e0 = __expf(st[kt][0]), e1 = __expf(st[kt][1]);
      float e2 = __expf(st[kt][2]), e3 = __expf(st[kt][3]);
      den += (e0 + e1) + (e2 + e3);
      s16x4 pa;
      pa[0] = f2b(e0); pa[1] = f2b(e1); pa[2] = f2b(e2); pa[3] = f2b(e3);
      oacc = mfma16x16x16_bf16(vfrag[kt], pa, oacc);
    }
    den += __shfl_xor(den, 16);
    den += __shfl_xor(den, 32);
    float inv = 1.f / den;
    s16x4 ov;
    ov[0] = f2b(oacc[0]*inv); ov[1] = f2b(oacc[1]*inv);
    ov[2] = f2b(oacc[2]*inv); ov[3] = f2b(oacc[3]*inv);
    *(s16x4*)&obs[((size_t)wid*256 + q0 + fr)*CC + head*16 + hi*4] = ov;
  }
}

// ---------------------------------------------------------------------------
// Kernel: FUSED conv3x3x3 + exln + norm2 (R19 2-t-chain structure).
// ---------------------------------------------------------------------------
__global__ __launch_bounds__(256) void conv_ln_kernel(
    const __hip_bfloat16* __restrict__ y1p, const float* __restrict__ wT,
    const float* __restrict__ cb,
    const float* __restrict__ exg, const float* __restrict__ exb,
    const float* __restrict__ n2g, const float* __restrict__ n2b,
    _Float16* __restrict__ yb, __hip_bfloat16* __restrict__ h2) {
  const int tid = threadIdx.x;
  const int sp = blockIdx.x*8 + (tid >> 5);      // spatial site 0..16383
  const int tp = (tid >> 4) & 1;                 // t-pair
  const int cbase = (tid & 15) * 8;              // 8-channel group
  const int w = sp & 31, h = (sp >> 5) & 31, d = sp >> 10;
  const int psite = ((d+1)*PH + (h+1))*PW + (w+1);
  const short* base = (const short*)y1p + (size_t)psite*512 + tp*2*CC + cbase;

  float acc[2][8];
  {
    f32x4 cb0 = *(const f32x4*)&cb[cbase];
    f32x4 cb1 = *(const f32x4*)&cb[cbase + 4];
#pragma unroll
    for (int t = 0; t < 2; ++t) {
      acc[t][0]=cb0.x; acc[t][1]=cb0.y; acc[t][2]=cb0.z; acc[t][3]=cb0.w;
      acc[t][4]=cb1.x; acc[t][5]=cb1.y; acc[t][6]=cb1.z; acc[t][7]=cb1.w;
    }
  }

#pragma unroll
  for (int dd = -1; dd <= 1; ++dd)
#pragma unroll
    for (int dh = -1; dh <= 1; ++dh)
#pragma unroll
      for (int dw = -1; dw <= 1; ++dw) {
        const int tap = ((dd+1)*3 + (dh+1))*3 + (dw+1);
        const int toff = ((dd*PH + dh)*PW + dw)*512;
        f32x4 w0 = *(const f32x4*)&wT[tap*CC + cbase];
        f32x4 w1 = *(const f32x4*)&wT[tap*CC + cbase + 4];
#pragma unroll
        for (int t = 0; t < 2; ++t) {
          s16x8 v = *(const s16x8*)(base + toff + t*CC);
          acc[t][0] = fmaf(b2f(v[0]), w0.x, acc[t][0]);
          acc[t][1] = fmaf(b2f(v[1]), w0.y, acc[t][1]);
          acc[t][2] = fmaf(b2f(v[2]), w0.z, acc[t][2]);
          acc[t][3] = fmaf(b2f(v[3]), w0.w, acc[t][3]);
          acc[t][4] = fmaf(b2f(v[4]), w1.x, acc[t][4]);
          acc[t][5] = fmaf(b2f(v[5]), w1.y, acc[t][5]);
          acc[t][6] = fmaf(b2f(v[6]), w1.z, acc[t][6]);
          acc[t][7] = fmaf(b2f(v[7]), w1.w, acc[t][7]);
        }
      }

  f32x4 eg0 = *(const f32x4*)&exg[cbase], eg1 = *(const f32x4*)&exg[cbase+4];
  f32x4 eb0 = *(const f32x4*)&exb[cbase], eb1 = *(const f32x4*)&exb[cbase+4];
  f32x4 ng0 = *(const f32x4*)&n2g[cbase], ng1 = *(const f32x4*)&n2g[cbase+4];
  f32x4 nb0 = *(const f32x4*)&n2b[cbase], nb1 = *(const f32x4*)&n2b[cbase+4];
  float eg[8] = {eg0.x,eg0.y,eg0.z,eg0.w,eg1.x,eg1.y,eg1.z,eg1.w};
  float eb[8] = {eb0.x,eb0.y,eb0.z,eb0.w,eb1.x,eb1.y,eb1.z,eb1.w};
  float ng[8] = {ng0.x,ng0.y,ng0.z,ng0.w,ng1.x,ng1.y,ng1.z,ng1.w};
  float nb[8] = {nb0.x,nb0.y,nb0.z,nb0.w,nb1.x,nb1.y,nb1.z,nb1.w};

#pragma unroll
  for (int t = 0; t < 2; ++t) {
    float s = 0.f, sq = 0.f;
#pragma unroll
    for (int c = 0; c < 8; ++c) { s += acc[t][c]; sq = fmaf(acc[t][c], acc[t][c], sq); }
#pragma unroll
    for (int m = 1; m <= 8; m <<= 1) { s += __shfl_xor(s, m); sq += __shfl_xor(sq, m); }
    float mean = s * (1.f/128.f);
    float var  = sq * (1.f/128.f) - mean*mean;
    float rstd = rsqrtf(var + LNEPS);
    float y[8];
    f16x8 yo;
#pragma unroll
    for (int c = 0; c < 8; ++c) {
      y[c] = (acc[t][c] - mean)*rstd*eg[c] + eb[c];
      yo[c] = (_Float16)y[c];
    }
    const int tok = sp*4 + tp*2 + t;
    *(f16x8*)&yb[(size_t)tok*CC + cbase] = yo;
    float s2 = 0.f, sq2 = 0.f;
#pragma unroll
    for (int c = 0; c < 8; ++c) { s2 += y[c]; sq2 = fmaf(y[c], y[c], sq2); }
#pragma unroll
    for (int m = 1; m <= 8; m <<= 1) { s2 += __shfl_xor(s2, m); sq2 += __shfl_xor(sq2, m); }
    float mean2 = s2 * (1.f/128.f);
    float var2  = sq2 * (1.f/128.f) - mean2*mean2;
    float rstd2 = rsqrtf(var2 + LNEPS);
    s16x8 ho;
#pragma unroll
    for (int c = 0; c < 8; ++c)
      ho[c] = f2b((y[c] - mean2)*rstd2*ng[c] + nb[c]);
    *(s16x8*)&((short*)h2)[(size_t)tok*CC + cbase] = ho;
  }
}

// ---------------------------------------------------------------------------
// Launch
// ---------------------------------------------------------------------------
extern "C" void kernel_launch(void* const* d_in, const int* in_sizes, int n_in,
                              void* d_out, int out_size, void* d_ws, size_t ws_size,
                              hipStream_t stream) {
  const float* x      = (const float*)d_in[0];
  const float* n1g    = (const float*)d_in[1];
  const float* n1b    = (const float*)d_in[2];
  const float* pos    = (const float*)d_in[3];
  const float* te     = (const float*)d_in[4];
  const float* qkv_w  = (const float*)d_in[5];
  const float* qkv_b  = (const float*)d_in[6];
  const float* proj_w = (const float*)d_in[7];
  const float* proj_b = (const float*)d_in[8];
  const float* conv_w = (const float*)d_in[9];
  const float* conv_b = (const float*)d_in[10];
  const float* exg    = (const float*)d_in[11];
  const float* exb    = (const float*)d_in[12];
  const float* n2g    = (const float*)d_in[13];
  const float* n2b    = (const float*)d_in[14];
  const float* fc1_w  = (const float*)d_in[15];
  const float* fc1_b  = (const float*)d_in[16];
  const float* fc2_w  = (const float*)d_in[17];
  const float* fc2_b  = (const float*)d_in[18];

  char* wsb = (char*)d_ws;
  __hip_bfloat16* wq  = (__hip_bfloat16*)(wsb);
  __hip_bfloat16* wp  = (__hip_bfloat16*)(wsb + 98304);
  __hip_bfloat16* w1  = (__hip_bfloat16*)(wsb + 131072);
  __hip_bfloat16* w2  = (__hip_bfloat16*)(wsb + 262144);
  float*          cwT = (float*)(wsb + 393216);

  const size_t A_OFF = (size_t)1 << 20;
  const size_t B_OFF = A_OFF + ((size_t)16 << 20);
  const size_t C_OFF = B_OFF + ((size_t)48 << 20);

  __hip_bfloat16* hbuf = (__hip_bfloat16*)(wsb + A_OFF);
  __hip_bfloat16* obuf = (__hip_bfloat16*)(wsb + A_OFF);
  __hip_bfloat16* h2in = (__hip_bfloat16*)(wsb + A_OFF);
  __hip_bfloat16* qkvb = (__hip_bfloat16*)(wsb + B_OFF);
  __hip_bfloat16* qb   = qkvb;
  __hip_bfloat16* kb   = qkvb + 8388608;
  __hip_bfloat16* vb   = qkvb + 16777216;
  __hip_bfloat16* y1p  = (__hip_bfloat16*)(wsb + B_OFF);
  _Float16* yb = (_Float16*)(wsb + B_OFF + ((size_t)24 << 20));
  __hip_bfloat16* gbuf = (__hip_bfloat16*)(wsb + C_OFF);

  setup_kernel<<<PREP_BLOCKS + LN1_BLOCKS, 256, 0, stream>>>(
      qkv_w, proj_w, fc1_w, fc2_w, conv_w, wq, wp, w1, w2, cwT,
      x, n1g, n1b, pos, te, hbuf);
  gemm_kernel<0, 128, 0><<<dim3(TOKS/128, 3), 256, 0, stream>>>(
      (const short*)hbuf, (const short*)wq, qkv_b, (void*)qkvb, nullptr);
  attn_mfma_kernel<<<NWIN*8, 256, 0, stream>>>(qb, kb, vb, obuf);
  border_zero_kernel<<<(PSITES*64 + 255)/256, 256, 0, stream>>>((short*)y1p);
  gemm_kernel<1, 128, 0><<<dim3(TOKS/128, 1), 256, 0, stream>>>(
      (const short*)obuf, (const short*)wp, proj_b, (void*)y1p, nullptr);
  conv_ln_kernel<<<16384/8, 256, 0, stream>>>(y1p, cwT, conv_b,
      exg, exb, n2g, n2b, yb, h2in);
  gemm_kernel<2, 128, 0><<<dim3(TOKS/128, 4), 256, 0, stream>>>(
      (const short*)h2in, (const short*)w1, fc1_b, (void*)gbuf, nullptr);
  gemm_kernel<3, 512, 1><<<dim3(TOKS/128, 1), 256, 0, stream>>>(
      (const short*)gbuf, (const short*)w2, fc2_b, (void*)d_out, yb);
}

// Round 22
// 164.926 us; speedup vs baseline: 1.0473x; 1.0243x over previous
//
#include <hip/hip_runtime.h>
#include <hip/hip_bf16.h>

// ---------------------------------------------------------------------------
// CrossFormerBlock on MI355X (gfx950)
// B=1 D=16 H=32 W=32 T=4 C=128, G=4, NH=8, HD=16, NW=256 windows, N=256 tok/win
// R22 (from R21 best=168.9us): border_zero merged INTO the proj dispatch —
// proj writes y1p interior, border blocks (blockIdx.x>=512) write the
// disjoint border sites concurrently. One fewer launch+gap. All math,
// tiles and schedules identical to R21.
// ---------------------------------------------------------------------------

typedef __attribute__((ext_vector_type(8))) short  s16x8;
typedef __attribute__((ext_vector_type(4))) short  s16x4;
typedef __attribute__((ext_vector_type(4))) float  f32x4;
typedef __attribute__((ext_vector_type(8))) _Float16 f16x8;
typedef __attribute__((ext_vector_type(4))) _Float16 f16x4;

#define CC    128
#define NWIN  256
#define TOKS  65536
#define SCALE 0.25f
#define LNEPS 1e-5f
#define PD 18
#define PH 34
#define PW 34
#define PSITES (PD*PH*PW)                // 20808
#define PREP_BLOCKS 782
#define LN1_BLOCKS (TOKS/8)
#define BORDER_BLOCKS ((PSITES*64 + 255)/256)   // 5202

__device__ __forceinline__ float b2f(short s) {
  union { unsigned u; float f; } c; c.u = ((unsigned)(unsigned short)s) << 16; return c.f;
}
__device__ __forceinline__ short f2b(float f) {
  __hip_bfloat16 h = __float2bfloat16(f);
  return *reinterpret_cast<short*>(&h);
}
__device__ __forceinline__ float fast_gelu(float x) {
  float u = 1.595769122f * x * fmaf(0.044715f, x*x, 1.0f);
  return x / (1.0f + __expf(-u));
}

__device__ __forceinline__ f32x4 mfma16x16x16_bf16(s16x4 a, s16x4 b, f32x4 c) {
#if __has_builtin(__builtin_amdgcn_mfma_f32_16x16x16_bf16)
  return __builtin_amdgcn_mfma_f32_16x16x16_bf16(a, b, c, 0, 0, 0);
#elif __has_builtin(__builtin_amdgcn_mfma_f32_16x16x16bf16_1k)
  return __builtin_amdgcn_mfma_f32_16x16x16bf16_1k(a, b, c, 0, 0, 0);
#else
  f32x4 d;
  asm("v_mfma_f32_16x16x16_bf16 %0, %1, %2, %3" : "=v"(d) : "v"(a), "v"(b), "v"(c));
  return d;
#endif
}

// async global->LDS, 16B per lane; lds base wave-uniform (HW appends lane*16).
__device__ __forceinline__ void gload16(const short* g, short* l) {
  __builtin_amdgcn_global_load_lds(
      (const __attribute__((address_space(1))) void*)g,
      (__attribute__((address_space(3))) void*)l, 16, 0, 0);
}

// ---------------------------------------------------------------------------
// Kernel: SETUP = weight prep (blocks 0..781) + LN1+PE (blocks 782..)
// ---------------------------------------------------------------------------
__global__ __launch_bounds__(256) void setup_kernel(
    const float* __restrict__ qkv_w, const float* __restrict__ proj_w,
    const float* __restrict__ fc1_w, const float* __restrict__ fc2_w,
    const float* __restrict__ conv_w,
    __hip_bfloat16* wq, __hip_bfloat16* wp,
    __hip_bfloat16* w1, __hip_bfloat16* w2, float* cwT,
    const float* __restrict__ x, const float* __restrict__ g,
    const float* __restrict__ b, const float* __restrict__ pos,
    const float* __restrict__ te, __hip_bfloat16* __restrict__ hb) {
  if (blockIdx.x < PREP_BLOCKS) {
    int idx = blockIdx.x * 256 + threadIdx.x;
    if (idx < 49152) {
      wq[idx] = __float2bfloat16(qkv_w[idx]);
    } else if (idx < 65536) {
      wp[idx - 49152] = __float2bfloat16(proj_w[idx - 49152]);
    } else if (idx < 131072) {
      w1[idx - 65536] = __float2bfloat16(fc1_w[idx - 65536]);
    } else if (idx < 196608) {
      w2[idx - 131072] = __float2bfloat16(fc2_w[idx - 131072]);
    } else if (idx < 196608 + 27*128) {
      int j = idx - 196608;
      int tap = j >> 7, c = j & 127;
      cwT[tap*128 + c] = conv_w[c*27 + tap];   // (C,1,3,3,3) -> (27,C)
    }
    return;
  }
  // ---- LN1 + PE: 32 lanes/token, f32x4 loads ----
  const int tid = threadIdx.x;
  const int tk = (blockIdx.x - PREP_BLOCKS)*8 + (tid >> 5);
  const int c4 = (tid & 31) * 4;
  const int wid = tk >> 8, n = tk & 255;
  const int t = n >> 6, gd = (n >> 4) & 3, gh = (n >> 2) & 3, gw = n & 3;
  const int wd = wid >> 6, wh = (wid >> 3) & 7, ww = wid & 7;
  const int d = wd*4 + gd, h = wh*4 + gh, w = ww*4 + gw;
  const size_t xoff = ((size_t)((d*32 + h)*32 + w)*4 + t) * CC;
  f32x4 v = *(const f32x4*)&x[xoff + c4];
  float s  = (v.x + v.y) + (v.z + v.w);
  float sq = (v.x*v.x + v.y*v.y) + (v.z*v.z + v.w*v.w);
#pragma unroll
  for (int m = 1; m <= 16; m <<= 1) { s += __shfl_xor(s, m); sq += __shfl_xor(sq, m); }
  const float mean = s * (1.f/128.f);
  const float var  = sq * (1.f/128.f) - mean*mean;
  const float rstd = rsqrtf(var + LNEPS);
  const int pb = ((gd*4 + gh)*4 + gw) * CC, tb = t * CC;
  f32x4 gv = *(const f32x4*)&g[c4];
  f32x4 bv = *(const f32x4*)&b[c4];
  f32x4 pv = *(const f32x4*)&pos[pb + c4];
  f32x4 tv = *(const f32x4*)&te[tb + c4];
  s16x4 o;
  o[0] = f2b((v.x - mean)*rstd*gv.x + bv.x + pv.x + tv.x);
  o[1] = f2b((v.y - mean)*rstd*gv.y + bv.y + pv.y + tv.y);
  o[2] = f2b((v.z - mean)*rstd*gv.z + bv.z + pv.z + tv.z);
  o[3] = f2b((v.w - mean)*rstd*gv.w + bv.w + pv.w + tv.w);
  *(s16x4*)&((short*)hb)[(size_t)tk*CC + c4] = o;
}

// ---------------------------------------------------------------------------
// GEMM template: 128x128 tile, BK=64, 4 waves, compile-time K (KK).
// Staging: global_load_lds width=16, LINEAR LDS [128][64].
// DB=0: single-buffer 2-barrier loop (32KB LDS -> 3 blocks/CU).
// DB=1 (fc2 only, K=512): 2-phase double-buffer, one drain per tile.
// MODE 0: qkv split; MODE 1: proj -> PADDED spatial scatter bf16, with
//   border-zero blocks appended (blockIdx.x >= TOKS/128, disjoint writes);
// MODE 2: fc1 + fast GELU; MODE 3: fc2 + bias + fp16 residual -> fp32 d_out
// ---------------------------------------------------------------------------
template <int MODE, int KK, int DB>
__global__ __launch_bounds__(256) void gemm_kernel(
    const short* __restrict__ Ag, const short* __restrict__ Wg,
    const float* __restrict__ bias,
    void* __restrict__ out0, const _Float16* __restrict__ resid) {
  if constexpr (MODE == 1) {
    // appended border-zero blocks: write y1p border sites (disjoint from
    // the interior sites proj writes). Block-uniform branch, whole block
    // returns -> no divergent barrier.
    if (blockIdx.x >= TOKS/128) {
      int idx = (blockIdx.x - TOKS/128)*256 + threadIdx.x;
      if (idx < PSITES*64) {
        int site = idx >> 6;
        int w = site % PW, hh = (site / PW) % PH, d = site / (PW*PH);
        if (d == 0 || d == PD-1 || hh == 0 || hh == PH-1 || w == 0 || w == PW-1)
          *(s16x8*)&((short*)out0)[(size_t)site*512 + (idx & 63)*8] = (s16x8)0;
      }
      return;
    }
  }
  __shared__ __align__(16) short As[DB + 1][128*64];
  __shared__ __align__(16) short Bs[DB + 1][128*64];
  const int tid = threadIdx.x;
  const int m0 = blockIdx.x * 128;
  const int n0 = blockIdx.y * 128;
  const int lane = tid & 63, wv = tid >> 6;
  const int wr = wv >> 1, wc = wv & 1;
  const int fr = lane & 15, kg = lane >> 4;

  f32x4 acc[4][4];
#pragma unroll
  for (int i = 0; i < 4; ++i)
#pragma unroll
    for (int j = 0; j < 4; ++j) acc[i][j] = (f32x4)0.f;

  if constexpr (DB == 0) {
#pragma unroll
    for (int kc = 0; kc < KK; kc += 64) {
      __syncthreads();
#pragma unroll
      for (int i = 0; i < 4; ++i) {
        const int e = i*2048 + tid*8;
        const int row = e >> 6, col = e & 63;
        gload16(Ag + (size_t)(m0 + row)*KK + kc + col, &As[0][i*2048 + wv*512]);
        gload16(Wg + (size_t)(n0 + row)*KK + kc + col, &Bs[0][i*2048 + wv*512]);
      }
      __syncthreads();
#pragma unroll
      for (int ks = 0; ks < 2; ++ks) {
        s16x8 a[4], b[4];
#pragma unroll
        for (int i = 0; i < 4; ++i)
          a[i] = *(const s16x8*)&As[0][(wr*64 + i*16 + fr)*64 + ks*32 + kg*8];
#pragma unroll
        for (int j = 0; j < 4; ++j)
          b[j] = *(const s16x8*)&Bs[0][(wc*64 + j*16 + fr)*64 + ks*32 + kg*8];
#pragma unroll
        for (int i = 0; i < 4; ++i)
#pragma unroll
          for (int j = 0; j < 4; ++j)
            acc[i][j] = __builtin_amdgcn_mfma_f32_16x16x32_bf16(b[j], a[i], acc[i][j], 0, 0, 0);
      }
    }
  } else {
    constexpr int NT = KK / 64;
#pragma unroll
    for (int i = 0; i < 4; ++i) {
      const int e = i*2048 + tid*8;
      const int row = e >> 6, col = e & 63;
      gload16(Ag + (size_t)(m0 + row)*KK + col, &As[0][i*2048 + wv*512]);
      gload16(Wg + (size_t)(n0 + row)*KK + col, &Bs[0][i*2048 + wv*512]);
    }
    __syncthreads();
#pragma unroll
    for (int t = 0; t < NT; ++t) {
      const int cur = t & 1;
      if (t + 1 < NT) {
        const int kc = (t + 1) * 64;
#pragma unroll
        for (int i = 0; i < 4; ++i) {
          const int e = i*2048 + tid*8;
          const int row = e >> 6, col = e & 63;
          gload16(Ag + (size_t)(m0 + row)*KK + kc + col, &As[cur^1][i*2048 + wv*512]);
          gload16(Wg + (size_t)(n0 + row)*KK + kc + col, &Bs[cur^1][i*2048 + wv*512]);
        }
      }
#pragma unroll
      for (int ks = 0; ks < 2; ++ks) {
        s16x8 a[4], b[4];
#pragma unroll
        for (int i = 0; i < 4; ++i)
          a[i] = *(const s16x8*)&As[cur][(wr*64 + i*16 + fr)*64 + ks*32 + kg*8];
#pragma unroll
        for (int j = 0; j < 4; ++j)
          b[j] = *(const s16x8*)&Bs[cur][(wc*64 + j*16 + fr)*64 + ks*32 + kg*8];
#pragma unroll
        for (int i = 0; i < 4; ++i)
#pragma unroll
          for (int j = 0; j < 4; ++j)
            acc[i][j] = __builtin_amdgcn_mfma_f32_16x16x32_bf16(b[j], a[i], acc[i][j], 0, 0, 0);
      }
      __syncthreads();
    }
  }

  const int nbb = n0 + wc*64 + kg*4;
  f32x4 bj4[4];
#pragma unroll
  for (int j = 0; j < 4; ++j) bj4[j] = *(const f32x4*)&bias[nbb + j*16];

#pragma unroll
  for (int i = 0; i < 4; ++i) {
    const int m = m0 + wr*64 + i*16 + fr;
    if constexpr (MODE == 0) {
      short* qs = (short*)out0;
      const int sec = n0 >> 7;
      const float scl = (sec == 0) ? SCALE : 1.0f;
      const int wid = m >> 8, ntok = m & 255;
      const int rowbase = sec*8388608 + (wid*8)*4096 + ntok*16 + (nbb & 15);
#pragma unroll
      for (int j = 0; j < 4; ++j) {
        const int head = ((nbb + j*16) >> 4) & 7;
        f32x4 v = acc[i][j];
        s16x4 o;
        o[0] = f2b(fmaf(v[0], scl, bj4[j].x*scl));
        o[1] = f2b(fmaf(v[1], scl, bj4[j].y*scl));
        o[2] = f2b(fmaf(v[2], scl, bj4[j].z*scl));
        o[3] = f2b(fmaf(v[3], scl, bj4[j].w*scl));
        *(s16x4*)&qs[rowbase + head*4096] = o;
      }
    } else if constexpr (MODE == 1) {
      short* y1o = (short*)out0;       // PADDED [18][34][34][4][128]
      const int wid = m >> 8, ntok = m & 255;
      const int t = ntok >> 6, gd = (ntok >> 4) & 3, gh = (ntok >> 2) & 3, gw = ntok & 3;
      const int wd = wid >> 6, wh = (wid >> 3) & 7, ww = wid & 7;
      const int sr = (((wd*4 + gd + 1)*PH + wh*4 + gh + 1)*PW + ww*4 + gw + 1)*4 + t;
      const int base = sr*CC + nbb;
#pragma unroll
      for (int j = 0; j < 4; ++j) {
        f32x4 v = acc[i][j];
        s16x4 o;
        o[0] = f2b(v[0] + bj4[j].x); o[1] = f2b(v[1] + bj4[j].y);
        o[2] = f2b(v[2] + bj4[j].z); o[3] = f2b(v[3] + bj4[j].w);
        *(s16x4*)&y1o[base + j*16] = o;
      }
    } else if constexpr (MODE == 2) {
      short* gp = (short*)out0;
      const int base = m*512 + nbb;
#pragma unroll
      for (int j = 0; j < 4; ++j) {
        f32x4 v = acc[i][j];
        s16x4 o;
        o[0] = f2b(fast_gelu(v[0] + bj4[j].x)); o[1] = f2b(fast_gelu(v[1] + bj4[j].y));
        o[2] = f2b(fast_gelu(v[2] + bj4[j].z)); o[3] = f2b(fast_gelu(v[3] + bj4[j].w));
        *(s16x4*)&gp[base + j*16] = o;
      }
    } else {
      float* outp = (float*)out0;
      const int base = m*CC + nbb;
#pragma unroll
      for (int j = 0; j < 4; ++j) {
        f32x4 v = acc[i][j];
        f16x4 rz = *(const f16x4*)&resid[base + j*16];
        f32x4 o;
        o.x = v[0] + bj4[j].x + (float)rz[0]; o.y = v[1] + bj4[j].y + (float)rz[1];
        o.z = v[2] + bj4[j].z + (float)rz[2]; o.w = v[3] + bj4[j].w + (float)rz[3];
        *(f32x4*)&outp[base + j*16] = o;
      }
    }
  }
}

// ---------------------------------------------------------------------------
// Kernel: MFMA window attention (unchanged from R2).
// ---------------------------------------------------------------------------
#define KPAD 20
#define VPAD 264
__global__ __launch_bounds__(256) void attn_mfma_kernel(
    const __hip_bfloat16* __restrict__ qb, const __hip_bfloat16* __restrict__ kb,
    const __hip_bfloat16* __restrict__ vb, __hip_bfloat16* __restrict__ ob) {
  __shared__ __align__(16) short kL[256*KPAD];
  __shared__ __align__(16) short vT[16*VPAD];
  const int bh = blockIdx.x;                // win*8 + head
  const int wid = bh >> 3, head = bh & 7;
  const int tid = threadIdx.x;
  const short* kg = (const short*)kb + (size_t)bh*4096;
  const short* vg = (const short*)vb + (size_t)bh*4096;
  const short* qg = (const short*)qb + (size_t)bh*4096;
  {
    s16x8 a0 = *(const s16x8*)&kg[tid*16];
    s16x8 a1 = *(const s16x8*)&kg[tid*16 + 8];
    *(s16x8*)&kL[tid*KPAD]     = a0;
    *(s16x8*)&kL[tid*KPAD + 8] = a1;
    s16x8 b0 = *(const s16x8*)&vg[tid*16];
    s16x8 b1 = *(const s16x8*)&vg[tid*16 + 8];
#pragma unroll
    for (int d = 0; d < 8; ++d) {
      vT[d*VPAD + tid]     = b0[d];
      vT[(d+8)*VPAD + tid] = b1[d];
    }
  }
  __syncthreads();
  const int wv = tid >> 6, lane = tid & 63;
  const int fr = lane & 15, hi = lane >> 4;
  s16x4 kfrag[16], vfrag[16];
#pragma unroll
  for (int t = 0; t < 16; ++t) {
    kfrag[t] = *(const s16x4*)&kL[(t*16 + fr)*KPAD + hi*4];
    vfrag[t] = *(const s16x4*)&vT[fr*VPAD + t*16 + hi*4];
  }
  short* obs = (short*)ob;
  for (int qt = 0; qt < 4; ++qt) {
    const int q0 = wv*64 + qt*16;
    s16x4 qfrag = *(const s16x4*)&qg[(q0 + fr)*16 + hi*4];
    f32x4 st[16];
#pragma unroll
    for (int kt = 0; kt < 16; ++kt)
      st[kt] = mfma16x16x16_bf16(kfrag[kt], qfrag, (f32x4)0.f);
    float den = 0.f;
    f32x4 oacc = (f32x4)0.f;
#pragma unroll
    for (int kt = 0; kt < 16; ++kt) {
      float e0 = __expf(st[kt][0]), e1 = __expf(st[kt][1]);
      float e2 = __expf(st[kt][2]), e3 = __expf(st[kt][3]);
      den += (e0 + e1) + (e2 + e3);
      s16x4 pa;
      pa[0] = f2b(e0); pa[1] = f2b(e1); pa[2] = f2b(e2); pa[3] = f2b(e3);
      oacc = mfma16x16x16_bf16(vfrag[kt], pa, oacc);
    }
    den += __shfl_xor(den, 16);
    den += __shfl_xor(den, 32);
    float inv = 1.f / den;
    s16x4 ov;
    ov[0] = f2b(oacc[0]*inv); ov[1] = f2b(oacc[1]*inv);
    ov[2] = f2b(oacc[2]*inv); ov[3] = f2b(oacc[3]*inv);
    *(s16x4*)&obs[((size_t)wid*256 + q0 + fr)*CC + head*16 + hi*4] = ov;
  }
}

// ---------------------------------------------------------------------------
// Kernel: FUSED conv3x3x3 + exln + norm2 (R19 2-t-chain structure).
// ---------------------------------------------------------------------------
__global__ __launch_bounds__(256) void conv_ln_kernel(
    const __hip_bfloat16* __restrict__ y1p, const float* __restrict__ wT,
    const float* __restrict__ cb,
    const float* __restrict__ exg, const float* __restrict__ exb,
    const float* __restrict__ n2g, const float* __restrict__ n2b,
    _Float16* __restrict__ yb, __hip_bfloat16* __restrict__ h2) {
  const int tid = threadIdx.x;
  const int sp = blockIdx.x*8 + (tid >> 5);      // spatial site 0..16383
  const int tp = (tid >> 4) & 1;                 // t-pair
  const int cbase = (tid & 15) * 8;              // 8-channel group
  const int w = sp & 31, h = (sp >> 5) & 31, d = sp >> 10;
  const int psite = ((d+1)*PH + (h+1))*PW + (w+1);
  const short* base = (const short*)y1p + (size_t)psite*512 + tp*2*CC + cbase;

  float acc[2][8];
  {
    f32x4 cb0 = *(const f32x4*)&cb[cbase];
    f32x4 cb1 = *(const f32x4*)&cb[cbase + 4];
#pragma unroll
    for (int t = 0; t < 2; ++t) {
      acc[t][0]=cb0.x; acc[t][1]=cb0.y; acc[t][2]=cb0.z; acc[t][3]=cb0.w;
      acc[t][4]=cb1.x; acc[t][5]=cb1.y; acc[t][6]=cb1.z; acc[t][7]=cb1.w;
    }
  }

#pragma unroll
  for (int dd = -1; dd <= 1; ++dd)
#pragma unroll
    for (int dh = -1; dh <= 1; ++dh)
#pragma unroll
      for (int dw = -1; dw <= 1; ++dw) {
        const int tap = ((dd+1)*3 + (dh+1))*3 + (dw+1);
        const int toff = ((dd*PH + dh)*PW + dw)*512;
        f32x4 w0 = *(const f32x4*)&wT[tap*CC + cbase];
        f32x4 w1 = *(const f32x4*)&wT[tap*CC + cbase + 4];
#pragma unroll
        for (int t = 0; t < 2; ++t) {
          s16x8 v = *(const s16x8*)(base + toff + t*CC);
          acc[t][0] = fmaf(b2f(v[0]), w0.x, acc[t][0]);
          acc[t][1] = fmaf(b2f(v[1]), w0.y, acc[t][1]);
          acc[t][2] = fmaf(b2f(v[2]), w0.z, acc[t][2]);
          acc[t][3] = fmaf(b2f(v[3]), w0.w, acc[t][3]);
          acc[t][4] = fmaf(b2f(v[4]), w1.x, acc[t][4]);
          acc[t][5] = fmaf(b2f(v[5]), w1.y, acc[t][5]);
          acc[t][6] = fmaf(b2f(v[6]), w1.z, acc[t][6]);
          acc[t][7] = fmaf(b2f(v[7]), w1.w, acc[t][7]);
        }
      }

  f32x4 eg0 = *(const f32x4*)&exg[cbase], eg1 = *(const f32x4*)&exg[cbase+4];
  f32x4 eb0 = *(const f32x4*)&exb[cbase], eb1 = *(const f32x4*)&exb[cbase+4];
  f32x4 ng0 = *(const f32x4*)&n2g[cbase], ng1 = *(const f32x4*)&n2g[cbase+4];
  f32x4 nb0 = *(const f32x4*)&n2b[cbase], nb1 = *(const f32x4*)&n2b[cbase+4];
  float eg[8] = {eg0.x,eg0.y,eg0.z,eg0.w,eg1.x,eg1.y,eg1.z,eg1.w};
  float eb[8] = {eb0.x,eb0.y,eb0.z,eb0.w,eb1.x,eb1.y,eb1.z,eb1.w};
  float ng[8] = {ng0.x,ng0.y,ng0.z,ng0.w,ng1.x,ng1.y,ng1.z,ng1.w};
  float nb[8] = {nb0.x,nb0.y,nb0.z,nb0.w,nb1.x,nb1.y,nb1.z,nb1.w};

#pragma unroll
  for (int t = 0; t < 2; ++t) {
    float s = 0.f, sq = 0.f;
#pragma unroll
    for (int c = 0; c < 8; ++c) { s += acc[t][c]; sq = fmaf(acc[t][c], acc[t][c], sq); }
#pragma unroll
    for (int m = 1; m <= 8; m <<= 1) { s += __shfl_xor(s, m); sq += __shfl_xor(sq, m); }
    float mean = s * (1.f/128.f);
    float var  = sq * (1.f/128.f) - mean*mean;
    float rstd = rsqrtf(var + LNEPS);
    float y[8];
    f16x8 yo;
#pragma unroll
    for (int c = 0; c < 8; ++c) {
      y[c] = (acc[t][c] - mean)*rstd*eg[c] + eb[c];
      yo[c] = (_Float16)y[c];
    }
    const int tok = sp*4 + tp*2 + t;
    *(f16x8*)&yb[(size_t)tok*CC + cbase] = yo;
    float s2 = 0.f, sq2 = 0.f;
#pragma unroll
    for (int c = 0; c < 8; ++c) { s2 += y[c]; sq2 = fmaf(y[c], y[c], sq2); }
#pragma unroll
    for (int m = 1; m <= 8; m <<= 1) { s2 += __shfl_xor(s2, m); sq2 += __shfl_xor(sq2, m); }
    float mean2 = s2 * (1.f/128.f);
    float var2  = sq2 * (1.f/128.f) - mean2*mean2;
    float rstd2 = rsqrtf(var2 + LNEPS);
    s16x8 ho;
#pragma unroll
    for (int c = 0; c < 8; ++c)
      ho[c] = f2b((y[c] - mean2)*rstd2*ng[c] + nb[c]);
    *(s16x8*)&((short*)h2)[(size_t)tok*CC + cbase] = ho;
  }
}

// ---------------------------------------------------------------------------
// Launch
// ---------------------------------------------------------------------------
extern "C" void kernel_launch(void* const* d_in, const int* in_sizes, int n_in,
                              void* d_out, int out_size, void* d_ws, size_t ws_size,
                              hipStream_t stream) {
  const float* x      = (const float*)d_in[0];
  const float* n1g    = (const float*)d_in[1];
  const float* n1b    = (const float*)d_in[2];
  const float* pos    = (const float*)d_in[3];
  const float* te     = (const float*)d_in[4];
  const float* qkv_w  = (const float*)d_in[5];
  const float* qkv_b  = (const float*)d_in[6];
  const float* proj_w = (const float*)d_in[7];
  const float* proj_b = (const float*)d_in[8];
  const float* conv_w = (const float*)d_in[9];
  const float* conv_b = (const float*)d_in[10];
  const float* exg    = (const float*)d_in[11];
  const float* exb    = (const float*)d_in[12];
  const float* n2g    = (const float*)d_in[13];
  const float* n2b    = (const float*)d_in[14];
  const float* fc1_w  = (const float*)d_in[15];
  const float* fc1_b  = (const float*)d_in[16];
  const float* fc2_w  = (const float*)d_in[17];
  const float* fc2_b  = (const float*)d_in[18];

  char* wsb = (char*)d_ws;
  __hip_bfloat16* wq  = (__hip_bfloat16*)(wsb);
  __hip_bfloat16* wp  = (__hip_bfloat16*)(wsb + 98304);
  __hip_bfloat16* w1  = (__hip_bfloat16*)(wsb + 131072);
  __hip_bfloat16* w2  = (__hip_bfloat16*)(wsb + 262144);
  float*          cwT = (float*)(wsb + 393216);

  const size_t A_OFF = (size_t)1 << 20;
  const size_t B_OFF = A_OFF + ((size_t)16 << 20);
  const size_t C_OFF = B_OFF + ((size_t)48 << 20);

  __hip_bfloat16* hbuf = (__hip_bfloat16*)(wsb + A_OFF);
  __hip_bfloat16* obuf = (__hip_bfloat16*)(wsb + A_OFF);
  __hip_bfloat16* h2in = (__hip_bfloat16*)(wsb + A_OFF);
  __hip_bfloat16* qkvb = (__hip_bfloat16*)(wsb + B_OFF);
  __hip_bfloat16* qb   = qkvb;
  __hip_bfloat16* kb   = qkvb + 8388608;
  __hip_bfloat16* vb   = qkvb + 16777216;
  __hip_bfloat16* y1p  = (__hip_bfloat16*)(wsb + B_OFF);
  _Float16* yb = (_Float16*)(wsb + B_OFF + ((size_t)24 << 20));
  __hip_bfloat16* gbuf = (__hip_bfloat16*)(wsb + C_OFF);

  setup_kernel<<<PREP_BLOCKS + LN1_BLOCKS, 256, 0, stream>>>(
      qkv_w, proj_w, fc1_w, fc2_w, conv_w, wq, wp, w1, w2, cwT,
      x, n1g, n1b, pos, te, hbuf);
  gemm_kernel<0, 128, 0><<<dim3(TOKS/128, 3), 256, 0, stream>>>(
      (const short*)hbuf, (const short*)wq, qkv_b, (void*)qkvb, nullptr);
  attn_mfma_kernel<<<NWIN*8, 256, 0, stream>>>(qb, kb, vb, obuf);
  // proj + border-zero merged: blocks >= TOKS/128 write the y1p border.
  gemm_kernel<1, 128, 0><<<dim3(TOKS/128 + BORDER_BLOCKS, 1), 256, 0, stream>>>(
      (const short*)obuf, (const short*)wp, proj_b, (void*)y1p, nullptr);
  conv_ln_kernel<<<16384/8, 256, 0, stream>>>(y1p, cwT, conv_b,
      exg, exb, n2g, n2b, yb, h2in);
  gemm_kernel<2, 128, 0><<<dim3(TOKS/128, 4), 256, 0, stream>>>(
      (const short*)h2in, (const short*)w1, fc1_b, (void*)gbuf, nullptr);
  gemm_kernel<3, 512, 1><<<dim3(TOKS/128, 1), 256, 0, stream>>>(
      (const short*)gbuf, (const short*)w2, fc2_b, (void*)d_out, yb);
}